// Round 1
// 95.052 us; speedup vs baseline: 1.0103x; 1.0103x over previous
//
#include <hip/hip_runtime.h>
#include <math.h>

#define EPSF 1e-6f

constexpr int B_ = 8, Q_ = 900, C1_ = 92, T_ = 1600;
constexpr int NROW = B_ * Q_;       // 7200
constexpr int RPB = 16;             // query rows per block
constexpr int TPB = 320;            // 5 waves; 5 x-blocks * 320 = 1600 targets
constexpr int LSTRIDE = 92;         // logits/probs row stride in LDS (floats)

// Single fused kernel: stages 16 rows of logits in LDS, computes softmax
// in-place (one wave per row, round-robin), derives per-pred-box and
// per-target quantities locally, then does the pairwise cost loop.
// No precompute kernel, no workspace round trip.
__global__ __launch_bounds__(TPB) void fused_cost_kernel(
    const float* __restrict__ logits,  // [NROW, 92]
    const float* __restrict__ pbox,    // [NROW, 4] corners
    const int*   __restrict__ ids,     // [T]
    const float* __restrict__ tbox,    // [T, 4] corners
    float* __restrict__ out)           // [NROW, T]
{
    __shared__ float sprobs[RPB * LSTRIDE];   // 16*92*4 = 5888 B
    __shared__ float spredd[RPB * 8];         // 512 B

    const int tid  = threadIdx.x;
    const int t    = blockIdx.x * TPB + tid;   // gridDim.x * TPB == T_
    const int row0 = blockIdx.y * RPB;

    // ---- stage logits: 16 rows x 92 = 1472 floats = 368 float4, contiguous.
    // row0*92 is divisible by 4, so the block's slice is float4-aligned.
    {
        const float4* gl4 = (const float4*)(logits + (size_t)row0 * C1_);
        float4* sl4 = (float4*)sprobs;
        sl4[tid] = gl4[tid];
        if (tid < RPB * C1_ / 4 - TPB)          // 368 - 320 = 48
            sl4[tid + TPB] = gl4[tid + TPB];
    }

    // ---- per-target derived data, registers for block lifetime ----
    const float4 tb4 = *(const float4*)(tbox + (size_t)t * 4);
    const int id = ids[t];
    const float tx1 = tb4.x, ty1 = tb4.y, tx2 = tb4.z, ty2 = tb4.w;
    const float w2 = tx2 - tx1, h2 = ty2 - ty1;
    const float area2  = w2 * h2;
    const float atan2t = atanf(w2 / (h2 + EPSF));
    const float sx2 = tx1 + tx2, sy2 = ty1 + ty2;

    // ---- pred-box derived data: threads 0..15, one row each ----
    if (tid < RPB) {
        const float4 pb4 = *(const float4*)(pbox + (size_t)(row0 + tid) * 4);
        const float w = pb4.z - pb4.x, h = pb4.w - pb4.y;
        float* d = spredd + tid * 8;
        d[0] = pb4.x; d[1] = pb4.y; d[2] = pb4.z; d[3] = pb4.w;
        d[4] = w * h;
        d[5] = atanf(w / (h + EPSF));
        d[6] = pb4.x + pb4.z;
        d[7] = pb4.y + pb4.w;
    }

    __syncthreads();

    // ---- softmax in-place on the 16 LDS rows: one wave per row ----
    {
        const int wave = tid >> 6;
        const int lane = tid & 63;
        for (int r = wave; r < RPB; r += TPB / 64) {
            float* row = sprobs + r * LSTRIDE;
            const float x0 = row[lane];                              // 92 > 64
            const float x1 = (lane + 64 < C1_) ? row[lane + 64] : -INFINITY;
            float m = fmaxf(x0, x1);
            #pragma unroll
            for (int off = 32; off; off >>= 1) m = fmaxf(m, __shfl_xor(m, off));
            const float e0 = __expf(x0 - m);
            const float e1 = (lane + 64 < C1_) ? __expf(x1 - m) : 0.0f;
            float s = e0 + e1;
            #pragma unroll
            for (int off = 32; off; off >>= 1) s += __shfl_xor(s, off);
            const float inv = 1.0f / s;
            row[lane] = e0 * inv;
            if (lane + 64 < C1_) row[lane + 64] = e1 * inv;
        }
    }

    __syncthreads();

    // ---- pairwise cost: 16 rows per thread, LDS-only inner loop + store ----
    float* outp = out + (size_t)row0 * T_ + t;
    #pragma unroll 4
    for (int r = 0; r < RPB; ++r) {
        const float4 pa = *(const float4*)(spredd + r * 8);
        const float4 pb = *(const float4*)(spredd + r * 8 + 4);
        const float px1 = pa.x, py1 = pa.y, px2 = pa.z, py2 = pa.w;
        const float area1 = pb.x, atan1t = pb.y, sx1 = pb.z, sy1 = pb.w;

        const float prob = sprobs[r * LSTRIDE + id];

        // intersection / union / iou
        const float ix1 = fmaxf(px1, tx1);
        const float iy1 = fmaxf(py1, ty1);
        const float ix2 = fminf(px2, tx2);
        const float iy2 = fminf(py2, ty2);
        const float inter = fmaxf(ix2 - ix1, 0.0f) * fmaxf(iy2 - iy1, 0.0f);
        const float uni = area1 + area2 - inter;
        const float iou = inter * __builtin_amdgcn_rcpf(uni + EPSF);

        // convex diag + center distance penalty
        const float cw = fmaxf(px2, tx2) - fminf(px1, tx1);
        const float ch = fmaxf(py2, ty2) - fminf(py1, ty1);
        const float diag = cw * cw + ch * ch;
        const float dx = sx2 - sx1, dy = sy2 - sy1;
        const float cdist = dx * dx + dy * dy;
        const float dist_pen = cdist * __builtin_amdgcn_rcpf(diag + EPSF) * 0.25f;

        // aspect-ratio term
        const float dat = atan2t - atan1t;
        const float v = (4.0f / (float)(M_PI * M_PI)) * dat * dat;
        const float av = v * v * __builtin_amdgcn_rcpf(1.0f + EPSF - iou + v);

        const float ciou = iou - dist_pen - av;

        // L1 bbox cost
        const float cost_bbox = fabsf(px1 - tx1) + fabsf(py1 - ty1) +
                                fabsf(px2 - tx2) + fabsf(py2 - ty2);

        __builtin_nontemporal_store(cost_bbox - prob - ciou, outp);
        outp += T_;
    }
}

extern "C" void kernel_launch(void* const* d_in, const int* in_sizes, int n_in,
                              void* d_out, int out_size, void* d_ws, size_t ws_size,
                              hipStream_t stream) {
    const float* logits = (const float*)d_in[0];  // [8,900,92]
    const float* pbox   = (const float*)d_in[1];  // [8,900,4]
    const int*   ids    = (const int*)d_in[2];    // [1600]
    const float* tbox   = (const float*)d_in[3];  // [1600,4]
    float* out = (float*)d_out;

    fused_cost_kernel<<<dim3(T_ / TPB, NROW / RPB), TPB, 0, stream>>>(
        logits, pbox, ids, tbox, out);
}